// Round 6
// baseline (425.308 us; speedup 1.0000x reference)
//
#include <hip/hip_runtime.h>

#define D 64
#define EDIM 16
#define CAP 64      // per-node bucket capacity; Poisson(16): P(deg>64) ~ 1e-20/node.

// Two-level binning parameters
#define T_A    2048   // edges per coarse-bin tile (8 per thread) -> 782 blocks
#define BSHIFT 9      // 512 nodes per coarse bucket
#define BRANGE 512
#define BCAP   9216   // coarse-bucket capacity: Poisson(8192) + 11 sigma

// ---------------------------------------------------------------------------
// Phase 1a: coarse bin. LDS-staged counting sort into ~196 coarse buckets.
// Record pack: src[0:17) | eid[17:38) | dst_lo[38:47)
// ---------------------------------------------------------------------------
__global__ __launch_bounds__(256) void coarse_bin_kernel(
    const int* __restrict__ dst, const int* __restrict__ src,
    long long* __restrict__ coarse, int* __restrict__ gcursor, int E)
{
    __shared__ long long      stage[T_A];
    __shared__ unsigned short stage_b[T_A];
    __shared__ int lcnt[256];
    __shared__ int loff[256];
    __shared__ int lbase[256];
    __shared__ int s_valid;

    const int t    = threadIdx.x;
    const int base = blockIdx.x * T_A;

    lcnt[t] = 0;
    __syncthreads();

    int       myb[8];
    int       myslot[8];
    long long myrec[8];
#pragma unroll
    for (int j = 0; j < 8; ++j) {
        const int i = base + t + j * 256;
        if (i < E) {
            const int d = dst[i];
            const int s = src[i];
            const int b = d >> BSHIFT;
            myb[j]   = b;
            myrec[j] = (long long)(unsigned)s
                     | ((long long)i << 17)
                     | ((long long)(d & (BRANGE - 1)) << 38);
            myslot[j] = atomicAdd(&lcnt[b], 1);
        } else {
            myb[j] = -1;
        }
    }
    __syncthreads();

    // exclusive scan of lcnt over 256 entries (Hillis-Steele, inclusive first)
    const int v = lcnt[t];
    loff[t] = v;
    __syncthreads();
    for (int off = 1; off < 256; off <<= 1) {
        const int add = (t >= off) ? loff[t - off] : 0;
        __syncthreads();
        loff[t] += add;
        __syncthreads();
    }
    if (t == 255) s_valid = loff[255];          // total valid records in tile
    const int excl = loff[t] - v;               // own exclusive value
    loff[t] = excl;                             // own-slot overwrite, no race
    // reserve global space per bucket (one padded atomic per non-empty bucket)
    if (v > 0) lbase[t] = atomicAdd(&gcursor[t * 16], v);
    else       lbase[t] = 0;
    __syncthreads();

    // place into LDS, dense and bucket-sorted
#pragma unroll
    for (int j = 0; j < 8; ++j) {
        if (myb[j] >= 0) {
            const int p = loff[myb[j]] + myslot[j];
            stage[p]   = myrec[j];
            stage_b[p] = (unsigned short)myb[j];
        }
    }
    __syncthreads();

    // flush: consecutive threads hit consecutive stage slots -> runs of the
    // same bucket map to consecutive global addresses (coalesced)
    const int nv = s_valid;
    for (int p = t; p < nv; p += 256) {
        const int b   = stage_b[p];
        const int rel = lbase[b] + (p - loff[b]);
        if (rel < BCAP)
            coarse[(size_t)b * BCAP + rel] = stage[p];
    }
}

// ---------------------------------------------------------------------------
// Phase 1b REWRITE (R5 lesson): the old refine issued 1.6M individual 8B
// scattered stores -> ~14-16 G scattered-store/s wall -> ~110us regardless
// of occupancy (R5 TLP probe was null). Here: counting-sort the bucket's
// records DENSE IN LDS, then write rec[] in output-slot order so consecutive
// threads hit consecutive addresses -> full-line coalesced stores only
// (~250K line txns total instead of 1.6M scattered).
// ---------------------------------------------------------------------------
__global__ __launch_bounds__(1024) void refine_sort_kernel(
    const long long* __restrict__ coarse, const int* __restrict__ gcursor,
    int2* __restrict__ rec, int* __restrict__ cnt, int N)
{
    extern __shared__ long long dense[];          // BCAP records (73.7 KB)
    __shared__ int lc[BRANGE];
    __shared__ int bs[BRANGE];

    const int t = threadIdx.x;
    const int b = blockIdx.x;

    if (t < BRANGE) lc[t] = 0;
    __syncthreads();

    const int m = min(gcursor[b * 16], BCAP);
    const long long* crs = coarse + (size_t)b * BCAP;

    // read my records (coalesced), histogram via LDS atomics, remember slots
    long long rp[9];
    int       rslot[9];
    int       rdlo[9];
    int       nmine = 0;
#pragma unroll
    for (int j = 0; j < 9; ++j) {               // 9*1024 >= BCAP
        const int i = t + j * 1024;
        if (i < m) {
            const long long p = crs[i];
            const int dlo = (int)((p >> 38) & (BRANGE - 1));
            rp[j]    = p;
            rdlo[j]  = dlo;
            rslot[j] = atomicAdd(&lc[dlo], 1);
            nmine    = j + 1;
        }
    }
    __syncthreads();

    // exclusive scan of lc[512] -> bs[512]
    if (t < BRANGE) bs[t] = lc[t];
    __syncthreads();
    for (int off = 1; off < BRANGE; off <<= 1) {
        int add = 0;
        if (t < BRANGE && t >= off) add = bs[t - off];
        __syncthreads();
        if (t < BRANGE) bs[t] += add;
        __syncthreads();
    }
    if (t < BRANGE) bs[t] -= lc[t];             // inclusive -> exclusive
    __syncthreads();

    // place records dense-sorted in LDS
#pragma unroll
    for (int j = 0; j < 9; ++j) {
        if (j < nmine)
            dense[bs[rdlo[j]] + rslot[j]] = rp[j];
    }
    __syncthreads();

    // coalesced write-out: iterate output slots in address order.
    // 64 consecutive idx = one node's 64 slots; exec-masked to cnt -> the
    // written prefix covers whole 64B lines with consecutive 8B lanes.
    const int nodebase = b << BSHIFT;
#pragma unroll
    for (int j = 0; j < (BRANGE * CAP) / 1024; ++j) {
        const int idx  = t + j * 1024;
        const int r    = idx >> 6;              // CAP = 64
        const int slot = idx & (CAP - 1);
        const int c    = min(lc[r], CAP);
        if (slot < c) {
            const long long p = dense[bs[r] + slot];
            rec[(size_t)(nodebase + r) * CAP + slot] =
                make_int2((int)(p & 0x1FFFF), (int)((p >> 17) & 0x1FFFFF));
        }
    }
    if (t < BRANGE) {
        const int node = nodebase + t;
        if (node < N) cnt[node] = min(lc[t], CAP);
    }
}

// ---------------------------------------------------------------------------
// Phase 2 (FUSED): gather-aggregate + 2-layer node MLP. Unchanged from R3
// (measured at the random-access fabric wall, ~1.45 TB/s beyond-L2).
// ---------------------------------------------------------------------------
__global__ __launch_bounds__(256, 4) void gather_mlp_kernel(
    const float* __restrict__ x,
    const int2*  __restrict__ rec,
    const int*   __restrict__ cnt,
    const float* __restrict__ edge_attr,
    const float* __restrict__ W_edge,
    const float* __restrict__ b_edge,
    const float* __restrict__ W1, const float* __restrict__ b1,
    const float* __restrict__ W2, const float* __restrict__ b2,
    float*       __restrict__ out,
    int N)
{
    __shared__ float W1s[D * D];
    __shared__ float W2s[D * D];
    __shared__ float hstage[4][D];
    __shared__ float tstage[4][D];

    const int t = threadIdx.x;
    {
        const float4* w1v = (const float4*)W1;
        const float4* w2v = (const float4*)W2;
        float4* w1s = (float4*)W1s;
        float4* w2s = (float4*)W2s;
#pragma unroll
        for (int i = 0; i < 4; ++i) {
            w1s[t + i * 256] = w1v[t + i * 256];
            w2s[t + i * 256] = w2v[t + i * 256];
        }
    }
    __syncthreads();   // uniform, before the divergent node loop

    const int lane = t & 63;
    const int u    = lane >> 4;      // edge slot in group-of-4
    const int c    = lane & 15;      // column quad
    const int wv   = t >> 6;
    const int wave   = blockIdx.x * 4 + wv;
    const int nwaves = gridDim.x * 4;

    float4 we[EDIM];
#pragma unroll
    for (int k = 0; k < EDIM; ++k)
        we[k] = *(const float4*)(W_edge + k * D + 4 * c);
    const float4 be  = *(const float4*)(b_edge + 4 * c);
    const float  b1v = b1[lane];
    const float  b2v = b2[lane];

    for (int n = wave; n < N; n += nwaves) {
        const int deg = min(cnt[n], CAP);
        const int2* bucket = rec + (size_t)n * CAP;
        float4 acc = make_float4(0.0f, 0.0f, 0.0f, 0.0f);

        for (int e = 0; e < deg; e += 4) {
            const int   ee  = e + u;
            const bool  ok  = ee < deg;
            const int   ec  = ok ? ee : (deg - 1);   // deg >= 1 inside loop
            const float msk = ok ? 1.0f : 0.0f;

            const int2   r  = bucket[ec];
            const float4 xv = *(const float4*)(x + (size_t)r.x * D + 4 * c);

            const float4* ap = (const float4*)(edge_attr + (size_t)r.y * EDIM);
            const float4 a0 = ap[0], a1 = ap[1], a2 = ap[2], a3 = ap[3];
            const float av[EDIM] = {a0.x, a0.y, a0.z, a0.w,
                                    a1.x, a1.y, a1.z, a1.w,
                                    a2.x, a2.y, a2.z, a2.w,
                                    a3.x, a3.y, a3.z, a3.w};
            float4 v = be;
#pragma unroll
            for (int k = 0; k < EDIM; ++k) {
                v.x = fmaf(av[k], we[k].x, v.x);
                v.y = fmaf(av[k], we[k].y, v.y);
                v.z = fmaf(av[k], we[k].z, v.z);
                v.w = fmaf(av[k], we[k].w, v.w);
            }
            acc.x = fmaf(fmaxf(xv.x + v.x, 0.0f), msk, acc.x);
            acc.y = fmaf(fmaxf(xv.y + v.y, 0.0f), msk, acc.y);
            acc.z = fmaf(fmaxf(xv.z + v.z, 0.0f), msk, acc.z);
            acc.w = fmaf(fmaxf(xv.w + v.w, 0.0f), msk, acc.w);
        }

        // reduce across the 4 edge slots (lane bits 4 and 5)
#pragma unroll
        for (int off = 16; off < 64; off <<= 1) {
            acc.x += __shfl_xor(acc.x, off, 64);
            acc.y += __shfl_xor(acc.y, off, 64);
            acc.z += __shfl_xor(acc.z, off, 64);
            acc.w += __shfl_xor(acc.w, off, 64);
        }

        // h = x[n] + aggr, staged into per-wave LDS by the u==0 lanes
        if (u == 0) {
            const float4 xn = *(const float4*)(x + (size_t)n * D + 4 * c);
            float4 o;
            o.x = xn.x + acc.x;
            o.y = xn.y + acc.y;
            o.z = xn.z + acc.z;
            o.w = xn.w + acc.w;
            *(float4*)(&hstage[wv][4 * c]) = o;
        }
        asm volatile("s_waitcnt lgkmcnt(0)" ::: "memory");

        // MLP layer 1: a1 = relu(h . W1[:,lane] + b1[lane])
        float acc1 = b1v;
#pragma unroll
        for (int k = 0; k < D; k += 4) {
            const float4 hv = *(const float4*)(&hstage[wv][k]);
            acc1 = fmaf(hv.x, W1s[(k + 0) * D + lane], acc1);
            acc1 = fmaf(hv.y, W1s[(k + 1) * D + lane], acc1);
            acc1 = fmaf(hv.z, W1s[(k + 2) * D + lane], acc1);
            acc1 = fmaf(hv.w, W1s[(k + 3) * D + lane], acc1);
        }
        tstage[wv][lane] = fmaxf(acc1, 0.0f);
        asm volatile("s_waitcnt lgkmcnt(0)" ::: "memory");

        // MLP layer 2: out = t . W2[:,lane] + b2[lane]
        float acc2 = b2v;
#pragma unroll
        for (int k = 0; k < D; k += 4) {
            const float4 tv = *(const float4*)(&tstage[wv][k]);
            acc2 = fmaf(tv.x, W2s[(k + 0) * D + lane], acc2);
            acc2 = fmaf(tv.y, W2s[(k + 1) * D + lane], acc2);
            acc2 = fmaf(tv.z, W2s[(k + 2) * D + lane], acc2);
            acc2 = fmaf(tv.w, W2s[(k + 3) * D + lane], acc2);
        }
        out[(size_t)n * D + lane] = acc2;
        asm volatile("s_waitcnt lgkmcnt(0)" ::: "memory");  // guard hstage reuse
    }
}

// ---------------------------------------------------------------------------
// Standalone MLP (fallback path only).
// ---------------------------------------------------------------------------
__global__ __launch_bounds__(256) void mlp_kernel(
    const float* __restrict__ W1, const float* __restrict__ b1,
    const float* __restrict__ W2, const float* __restrict__ b2,
    float* inout, int N)
{
    __shared__ float W1s[D * D];
    __shared__ float W2s[D * D];
    __shared__ float hbuf[4][D];
    __shared__ float tbuf[4][D];

    const int t = threadIdx.x;
    const float4* w1v = (const float4*)W1;
    const float4* w2v = (const float4*)W2;
    float4* w1s = (float4*)W1s;
    float4* w2s = (float4*)W2s;
#pragma unroll
    for (int i = 0; i < 4; ++i) {
        w1s[t + i * 256] = w1v[t + i * 256];
        w2s[t + i * 256] = w2v[t + i * 256];
    }
    __syncthreads();

    const int lane = t & 63;
    const int wv   = t >> 6;
    const float b1v = b1[lane];
    const float b2v = b2[lane];

    for (int base = blockIdx.x * 4; base < N; base += gridDim.x * 4) {
        const int    node = base + wv;
        const size_t off  = (size_t)node * D + lane;

        hbuf[wv][lane] = inout[off];
        __syncthreads();

        float acc = b1v;
#pragma unroll
        for (int k = 0; k < D; k += 4) {
            const float4 hv = *(const float4*)(&hbuf[wv][k]);
            acc = fmaf(hv.x, W1s[(k + 0) * D + lane], acc);
            acc = fmaf(hv.y, W1s[(k + 1) * D + lane], acc);
            acc = fmaf(hv.z, W1s[(k + 2) * D + lane], acc);
            acc = fmaf(hv.w, W1s[(k + 3) * D + lane], acc);
        }
        tbuf[wv][lane] = fmaxf(acc, 0.0f);
        __syncthreads();

        float acc2 = b2v;
#pragma unroll
        for (int k = 0; k < D; k += 4) {
            const float4 tv = *(const float4*)(&tbuf[wv][k]);
            acc2 = fmaf(tv.x, W2s[(k + 0) * D + lane], acc2);
            acc2 = fmaf(tv.y, W2s[(k + 1) * D + lane], acc2);
            acc2 = fmaf(tv.z, W2s[(k + 2) * D + lane], acc2);
            acc2 = fmaf(tv.w, W2s[(k + 3) * D + lane], acc2);
        }
        inout[off] = acc2;
        __syncthreads();   // protect hbuf/tbuf reuse across iterations
    }
}

// ---------------------------------------------------------------------------
// Fallback path kernels (only if ws_size too small — not expected).
// ---------------------------------------------------------------------------
__global__ __launch_bounds__(256) void edge_atomic_kernel(
    const float* __restrict__ x,
    const int*   __restrict__ src,
    const int*   __restrict__ dst,
    const float* __restrict__ edge_attr,
    const float* __restrict__ W_edge,
    const float* __restrict__ b_edge,
    float*       __restrict__ aggr,
    int E)
{
    const int lane   = threadIdx.x & 63;
    const int wave   = blockIdx.x * 4 + (threadIdx.x >> 6);
    const int nwaves = gridDim.x * 4;

    float we[EDIM];
#pragma unroll
    for (int k = 0; k < EDIM; ++k) we[k] = W_edge[k * D + lane];
    const float be = b_edge[lane];

    for (int i = wave; i < E; i += nwaves) {
        const int s = src[i];
        const int d = dst[i];
        const float4* eap = (const float4*)(edge_attr + (size_t)i * EDIM);
        float acc = be;
#pragma unroll
        for (int c = 0; c < 4; ++c) {
            const float4 ea = eap[c];
            acc = fmaf(ea.x, we[4 * c + 0], acc);
            acc = fmaf(ea.y, we[4 * c + 1], acc);
            acc = fmaf(ea.z, we[4 * c + 2], acc);
            acc = fmaf(ea.w, we[4 * c + 3], acc);
        }
        float m = fmaxf(x[(size_t)s * D + lane] + acc, 0.0f);
        atomicAdd(&aggr[(size_t)d * D + lane], m);
    }
}

__global__ __launch_bounds__(256) void add_x_kernel(
    const float* __restrict__ x, float* __restrict__ h, size_t n)
{
    size_t i = (size_t)blockIdx.x * blockDim.x + threadIdx.x;
    size_t stride = (size_t)gridDim.x * blockDim.x;
    for (; i < n; i += stride) h[i] += x[i];
}

// ---------------------------------------------------------------------------
// d_ws layout: rec[N*CAP] int2 | coarse[kc*BCAP] ll | cnt[N] int | gcursor[256*16]
// total = 51.2 MB + 14.45 MB + 0.4 MB + 16 KB ~= 66.1 MB.
// ---------------------------------------------------------------------------
extern "C" void kernel_launch(void* const* d_in, const int* in_sizes, int n_in,
                              void* d_out, int out_size, void* d_ws, size_t ws_size,
                              hipStream_t stream)
{
    const float* x      = (const float*)d_in[0];
    const int*   eidx   = (const int*)d_in[1];
    const float* eattr  = (const float*)d_in[2];
    const float* W_edge = (const float*)d_in[3];
    const float* b_edge = (const float*)d_in[4];
    const float* W1     = (const float*)d_in[5];
    const float* b1     = (const float*)d_in[6];
    const float* W2     = (const float*)d_in[7];
    const float* b2     = (const float*)d_in[8];
    float*       out    = (float*)d_out;

    const int E = in_sizes[1] / 2;      // 1,600,000
    const int N = in_sizes[0] / D;      // 100,000

    const int* src = eidx;
    const int* dst = eidx + E;

    const int kc = (N + BRANGE - 1) >> BSHIFT;   // coarse bucket count (196)

    const size_t sz_rec    = (size_t)N * CAP * sizeof(int2);
    const size_t sz_coarse = (size_t)kc * BCAP * sizeof(long long);
    const size_t sz_cnt    = (size_t)N * sizeof(int);
    const size_t sz_gcur   = 256 * 16 * sizeof(int);
    const size_t need      = sz_rec + sz_coarse + sz_cnt + sz_gcur;

    if (ws_size >= need) {
        char* p = (char*)d_ws;
        int2*      rec     = (int2*)p;                      p += sz_rec;
        long long* coarse  = (long long*)p;                 p += sz_coarse;
        int*       cnt     = (int*)p;                       p += sz_cnt;
        int*       gcursor = (int*)p;

        hipMemsetAsync(gcursor, 0, sz_gcur, stream);
        const int gridA = (E + T_A - 1) / T_A;
        coarse_bin_kernel<<<gridA, 256, 0, stream>>>(dst, src, coarse, gcursor, E);
        refine_sort_kernel<<<kc, 1024, BCAP * sizeof(long long), stream>>>(
            coarse, gcursor, rec, cnt, N);
        gather_mlp_kernel<<<4096, 256, 0, stream>>>(x, rec, cnt,
                                                    eattr, W_edge, b_edge,
                                                    W1, b1, W2, b2, out, N);
    } else {
        // Fallback: atomic path (3 dispatches + memset).
        hipMemsetAsync(out, 0, (size_t)N * D * sizeof(float), stream);
        edge_atomic_kernel<<<2048, 256, 0, stream>>>(x, src, dst, eattr,
                                                     W_edge, b_edge, out, E);
        add_x_kernel<<<1024, 256, 0, stream>>>(x, out, (size_t)N * D);
        mlp_kernel<<<2048, 256, 0, stream>>>(W1, b1, W2, b2, out, N);
    }
}

// Round 7
// 410.174 us; speedup vs baseline: 1.0369x; 1.0369x over previous
//
#include <hip/hip_runtime.h>
#include <hip/hip_fp16.h>

#define D 64
#define EDIM 16
#define CAP 64      // fallback-path only now (CSR path has no cap)

// Two-level binning parameters
#define T_A    2048   // edges per coarse-bin tile (8 per thread)
#define BSHIFT 9      // 512 nodes per coarse bucket
#define BRANGE 512
#define BCAP   9216   // coarse-bucket capacity: Poisson(8192) + 11 sigma

// ---------------------------------------------------------------------------
// Phase 0: x -> fp16 copy (sequential, ~38 MB moved, ~7us).
// Rationale (R6): gather is a random-line-touch wall; fp32 x rows = 4 lines
// of the ~21 per 4-edge group (6.4M of 8.4M total touches). fp16 rows = 2
// lines. Residual (1+eps)*x stays fp32-exact in gather.
// ---------------------------------------------------------------------------
__global__ __launch_bounds__(256) void convert_x_kernel(
    const float* __restrict__ x, __half* __restrict__ xh, int n4)
{
    int i = blockIdx.x * blockDim.x + threadIdx.x;
    const int stride = gridDim.x * blockDim.x;
    for (; i < n4; i += stride) {
        const float4 v = ((const float4*)x)[i];
        __half2 a = __float22half2_rn(make_float2(v.x, v.y));
        __half2 b = __float22half2_rn(make_float2(v.z, v.w));
        uint2 u;
        u.x = *(unsigned*)&a;
        u.y = *(unsigned*)&b;
        ((uint2*)xh)[i] = u;
    }
}

// ---------------------------------------------------------------------------
// Phase 1a: coarse bin. LDS-staged counting sort into ~196 coarse buckets.
// Record pack: src[0:17) | eid[17:38) | dst_lo[38:47)
// ---------------------------------------------------------------------------
__global__ __launch_bounds__(256) void coarse_bin_kernel(
    const int* __restrict__ dst, const int* __restrict__ src,
    long long* __restrict__ coarse, int* __restrict__ gcursor, int E)
{
    __shared__ long long      stage[T_A];
    __shared__ unsigned short stage_b[T_A];
    __shared__ int lcnt[256];
    __shared__ int loff[256];
    __shared__ int lbase[256];
    __shared__ int s_valid;

    const int t    = threadIdx.x;
    const int base = blockIdx.x * T_A;

    lcnt[t] = 0;
    __syncthreads();

    int       myb[8];
    int       myslot[8];
    long long myrec[8];
#pragma unroll
    for (int j = 0; j < 8; ++j) {
        const int i = base + t + j * 256;
        if (i < E) {
            const int d = dst[i];
            const int s = src[i];
            const int b = d >> BSHIFT;
            myb[j]   = b;
            myrec[j] = (long long)(unsigned)s
                     | ((long long)i << 17)
                     | ((long long)(d & (BRANGE - 1)) << 38);
            myslot[j] = atomicAdd(&lcnt[b], 1);
        } else {
            myb[j] = -1;
        }
    }
    __syncthreads();

    // exclusive scan of lcnt over 256 entries (Hillis-Steele, inclusive first)
    const int v = lcnt[t];
    loff[t] = v;
    __syncthreads();
    for (int off = 1; off < 256; off <<= 1) {
        const int add = (t >= off) ? loff[t - off] : 0;
        __syncthreads();
        loff[t] += add;
        __syncthreads();
    }
    if (t == 255) s_valid = loff[255];          // total valid records in tile
    const int excl = loff[t] - v;               // own exclusive value
    loff[t] = excl;                             // own-slot overwrite, no race
    // reserve global space per bucket (one padded atomic per non-empty bucket)
    if (v > 0) lbase[t] = atomicAdd(&gcursor[t * 16], v);
    else       lbase[t] = 0;
    __syncthreads();

    // place into LDS, dense and bucket-sorted
#pragma unroll
    for (int j = 0; j < 8; ++j) {
        if (myb[j] >= 0) {
            const int p = loff[myb[j]] + myslot[j];
            stage[p]   = myrec[j];
            stage_b[p] = (unsigned short)myb[j];
        }
    }
    __syncthreads();

    // flush: runs of the same bucket -> consecutive global addresses
    const int nv = s_valid;
    for (int p = t; p < nv; p += 256) {
        const int b   = stage_b[p];
        const int rel = lbase[b] + (p - loff[b]);
        if (rel < BCAP)
            coarse[(size_t)b * BCAP + rel] = stage[p];
    }
}

// ---------------------------------------------------------------------------
// Phase 1b: refine -> dense CSR. Per coarse bucket: histogram 512 node
// counters, local scan, place dense-sorted in LDS, straight coalesced copy
// to rec[bucket_start + i]. meta[n] = (start, deg). No CAP approximation.
// bucket_start from a 256-wide parallel scan over gcursor (kc=196 <= 256).
// ---------------------------------------------------------------------------
__global__ __launch_bounds__(1024) void refine_csr_kernel(
    const long long* __restrict__ coarse, const int* __restrict__ gcursor,
    int2* __restrict__ rec, int2* __restrict__ meta, int N, int kc)
{
    extern __shared__ long long dense[];          // BCAP records (73.7 KB)
    __shared__ int lc[BRANGE];
    __shared__ int bs[BRANGE];
    __shared__ int gb[256];

    const int t = threadIdx.x;
    const int b = blockIdx.x;

    if (t < BRANGE) lc[t] = 0;
    if (t < 256) gb[t] = (t < kc) ? min(gcursor[t * 16], BCAP) : 0;
    __syncthreads();

    // inclusive scan of gb[256] (first 256 threads)
    for (int off = 1; off < 256; off <<= 1) {
        int add = 0;
        if (t < 256 && t >= off) add = gb[t - off];
        __syncthreads();
        if (t < 256) gb[t] += add;
        __syncthreads();
    }
    const int bstart = (b == 0) ? 0 : gb[b - 1];
    const int m      = min(gcursor[b * 16], BCAP);
    const long long* crs = coarse + (size_t)b * BCAP;

    // read records (coalesced), histogram via LDS atomics, remember slots
    long long rp[9];
    int       rslot[9];
    int       rdlo[9];
    int       nmine = 0;
#pragma unroll
    for (int j = 0; j < 9; ++j) {               // 9*1024 >= BCAP
        const int i = t + j * 1024;
        if (i < m) {
            const long long p = crs[i];
            const int dlo = (int)((p >> 38) & (BRANGE - 1));
            rp[j]    = p;
            rdlo[j]  = dlo;
            rslot[j] = atomicAdd(&lc[dlo], 1);
            nmine    = j + 1;
        }
    }
    __syncthreads();

    // exclusive scan of lc[512] -> bs[512]
    if (t < BRANGE) bs[t] = lc[t];
    __syncthreads();
    for (int off = 1; off < BRANGE; off <<= 1) {
        int add = 0;
        if (t < BRANGE && t >= off) add = bs[t - off];
        __syncthreads();
        if (t < BRANGE) bs[t] += add;
        __syncthreads();
    }
    if (t < BRANGE) bs[t] -= lc[t];             // inclusive -> exclusive
    __syncthreads();

    // place records dense-sorted (node-major) in LDS
#pragma unroll
    for (int j = 0; j < 9; ++j) {
        if (j < nmine)
            dense[bs[rdlo[j]] + rslot[j]] = rp[j];
    }
    __syncthreads();

    // straight coalesced copy-out: dense[] is already in CSR order
    for (int i = t; i < m; i += 1024) {
        const long long p = dense[i];
        rec[bstart + i] =
            make_int2((int)(p & 0x1FFFF), (int)((p >> 17) & 0x1FFFFF));
    }
    if (t < BRANGE) {
        const int node = (b << BSHIFT) + t;
        if (node < N) meta[node] = make_int2(bstart + bs[t], lc[t]);
    }
}

// ---------------------------------------------------------------------------
// Phase 2 (FUSED): gather-aggregate + 2-layer node MLP.
// Changes vs R6: x message reads from fp16 xh (2 lines/row instead of 4);
// CSR meta/rec instead of CAP buckets. Residual x stays fp32.
// ---------------------------------------------------------------------------
__global__ __launch_bounds__(256, 4) void gather_mlp_kernel(
    const float*  __restrict__ x,
    const __half* __restrict__ xh,
    const int2*   __restrict__ rec,
    const int2*   __restrict__ meta,
    const float*  __restrict__ edge_attr,
    const float*  __restrict__ W_edge,
    const float*  __restrict__ b_edge,
    const float* __restrict__ W1, const float* __restrict__ b1,
    const float* __restrict__ W2, const float* __restrict__ b2,
    float*       __restrict__ out,
    int N)
{
    __shared__ float W1s[D * D];
    __shared__ float W2s[D * D];
    __shared__ float hstage[4][D];
    __shared__ float tstage[4][D];

    const int t = threadIdx.x;
    {
        const float4* w1v = (const float4*)W1;
        const float4* w2v = (const float4*)W2;
        float4* w1s = (float4*)W1s;
        float4* w2s = (float4*)W2s;
#pragma unroll
        for (int i = 0; i < 4; ++i) {
            w1s[t + i * 256] = w1v[t + i * 256];
            w2s[t + i * 256] = w2v[t + i * 256];
        }
    }
    __syncthreads();   // uniform, before the divergent node loop

    const int lane = t & 63;
    const int u    = lane >> 4;      // edge slot in group-of-4
    const int c    = lane & 15;      // column quad
    const int wv   = t >> 6;
    const int wave   = blockIdx.x * 4 + wv;
    const int nwaves = gridDim.x * 4;

    float4 we[EDIM];
#pragma unroll
    for (int k = 0; k < EDIM; ++k)
        we[k] = *(const float4*)(W_edge + k * D + 4 * c);
    const float4 be  = *(const float4*)(b_edge + 4 * c);
    const float  b1v = b1[lane];
    const float  b2v = b2[lane];

    for (int n = wave; n < N; n += nwaves) {
        const int2 md  = meta[n];
        const int  deg = md.y;
        const int2* bucket = rec + md.x;
        float4 acc = make_float4(0.0f, 0.0f, 0.0f, 0.0f);

        for (int e = 0; e < deg; e += 4) {
            const int   ee  = e + u;
            const bool  ok  = ee < deg;
            const int   ec  = ok ? ee : (deg - 1);   // deg >= 1 inside loop
            const float msk = ok ? 1.0f : 0.0f;

            const int2 r = bucket[ec];

            // fp16 x row: 4 halves = 8 B per lane (2 lines per row)
            const uint2 xu = *(const uint2*)(xh + (size_t)r.x * D + 4 * c);
            const float2 f01 = __half22float2(*(const __half2*)&xu.x);
            const float2 f23 = __half22float2(*(const __half2*)&xu.y);

            const float4* ap = (const float4*)(edge_attr + (size_t)r.y * EDIM);
            const float4 a0 = ap[0], a1 = ap[1], a2 = ap[2], a3 = ap[3];
            const float av[EDIM] = {a0.x, a0.y, a0.z, a0.w,
                                    a1.x, a1.y, a1.z, a1.w,
                                    a2.x, a2.y, a2.z, a2.w,
                                    a3.x, a3.y, a3.z, a3.w};
            float4 v = be;
#pragma unroll
            for (int k = 0; k < EDIM; ++k) {
                v.x = fmaf(av[k], we[k].x, v.x);
                v.y = fmaf(av[k], we[k].y, v.y);
                v.z = fmaf(av[k], we[k].z, v.z);
                v.w = fmaf(av[k], we[k].w, v.w);
            }
            acc.x = fmaf(fmaxf(f01.x + v.x, 0.0f), msk, acc.x);
            acc.y = fmaf(fmaxf(f01.y + v.y, 0.0f), msk, acc.y);
            acc.z = fmaf(fmaxf(f23.x + v.z, 0.0f), msk, acc.z);
            acc.w = fmaf(fmaxf(f23.y + v.w, 0.0f), msk, acc.w);
        }

        // reduce across the 4 edge slots (lane bits 4 and 5)
#pragma unroll
        for (int off = 16; off < 64; off <<= 1) {
            acc.x += __shfl_xor(acc.x, off, 64);
            acc.y += __shfl_xor(acc.y, off, 64);
            acc.z += __shfl_xor(acc.z, off, 64);
            acc.w += __shfl_xor(acc.w, off, 64);
        }

        // h = x[n] + aggr (residual in exact fp32), staged into per-wave LDS
        if (u == 0) {
            const float4 xn = *(const float4*)(x + (size_t)n * D + 4 * c);
            float4 o;
            o.x = xn.x + acc.x;
            o.y = xn.y + acc.y;
            o.z = xn.z + acc.z;
            o.w = xn.w + acc.w;
            *(float4*)(&hstage[wv][4 * c]) = o;
        }
        asm volatile("s_waitcnt lgkmcnt(0)" ::: "memory");

        // MLP layer 1: a1 = relu(h . W1[:,lane] + b1[lane])
        float acc1 = b1v;
#pragma unroll
        for (int k = 0; k < D; k += 4) {
            const float4 hv = *(const float4*)(&hstage[wv][k]);
            acc1 = fmaf(hv.x, W1s[(k + 0) * D + lane], acc1);
            acc1 = fmaf(hv.y, W1s[(k + 1) * D + lane], acc1);
            acc1 = fmaf(hv.z, W1s[(k + 2) * D + lane], acc1);
            acc1 = fmaf(hv.w, W1s[(k + 3) * D + lane], acc1);
        }
        tstage[wv][lane] = fmaxf(acc1, 0.0f);
        asm volatile("s_waitcnt lgkmcnt(0)" ::: "memory");

        // MLP layer 2: out = t . W2[:,lane] + b2[lane]
        float acc2 = b2v;
#pragma unroll
        for (int k = 0; k < D; k += 4) {
            const float4 tv = *(const float4*)(&tstage[wv][k]);
            acc2 = fmaf(tv.x, W2s[(k + 0) * D + lane], acc2);
            acc2 = fmaf(tv.y, W2s[(k + 1) * D + lane], acc2);
            acc2 = fmaf(tv.z, W2s[(k + 2) * D + lane], acc2);
            acc2 = fmaf(tv.w, W2s[(k + 3) * D + lane], acc2);
        }
        out[(size_t)n * D + lane] = acc2;
        asm volatile("s_waitcnt lgkmcnt(0)" ::: "memory");  // guard hstage reuse
    }
}

// ---------------------------------------------------------------------------
// Standalone MLP (fallback path only).
// ---------------------------------------------------------------------------
__global__ __launch_bounds__(256) void mlp_kernel(
    const float* __restrict__ W1, const float* __restrict__ b1,
    const float* __restrict__ W2, const float* __restrict__ b2,
    float* inout, int N)
{
    __shared__ float W1s[D * D];
    __shared__ float W2s[D * D];
    __shared__ float hbuf[4][D];
    __shared__ float tbuf[4][D];

    const int t = threadIdx.x;
    const float4* w1v = (const float4*)W1;
    const float4* w2v = (const float4*)W2;
    float4* w1s = (float4*)W1s;
    float4* w2s = (float4*)W2s;
#pragma unroll
    for (int i = 0; i < 4; ++i) {
        w1s[t + i * 256] = w1v[t + i * 256];
        w2s[t + i * 256] = w2v[t + i * 256];
    }
    __syncthreads();

    const int lane = t & 63;
    const int wv   = t >> 6;
    const float b1v = b1[lane];
    const float b2v = b2[lane];

    for (int base = blockIdx.x * 4; base < N; base += gridDim.x * 4) {
        const int    node = base + wv;
        const size_t off  = (size_t)node * D + lane;

        hbuf[wv][lane] = inout[off];
        __syncthreads();

        float acc = b1v;
#pragma unroll
        for (int k = 0; k < D; k += 4) {
            const float4 hv = *(const float4*)(&hbuf[wv][k]);
            acc = fmaf(hv.x, W1s[(k + 0) * D + lane], acc);
            acc = fmaf(hv.y, W1s[(k + 1) * D + lane], acc);
            acc = fmaf(hv.z, W1s[(k + 2) * D + lane], acc);
            acc = fmaf(hv.w, W1s[(k + 3) * D + lane], acc);
        }
        tbuf[wv][lane] = fmaxf(acc, 0.0f);
        __syncthreads();

        float acc2 = b2v;
#pragma unroll
        for (int k = 0; k < D; k += 4) {
            const float4 tv = *(const float4*)(&tbuf[wv][k]);
            acc2 = fmaf(tv.x, W2s[(k + 0) * D + lane], acc2);
            acc2 = fmaf(tv.y, W2s[(k + 1) * D + lane], acc2);
            acc2 = fmaf(tv.z, W2s[(k + 2) * D + lane], acc2);
            acc2 = fmaf(tv.w, W2s[(k + 3) * D + lane], acc2);
        }
        inout[off] = acc2;
        __syncthreads();   // protect hbuf/tbuf reuse across iterations
    }
}

// ---------------------------------------------------------------------------
// Fallback path kernels (only if ws_size too small — not expected).
// ---------------------------------------------------------------------------
__global__ __launch_bounds__(256) void edge_atomic_kernel(
    const float* __restrict__ x,
    const int*   __restrict__ src,
    const int*   __restrict__ dst,
    const float* __restrict__ edge_attr,
    const float* __restrict__ W_edge,
    const float* __restrict__ b_edge,
    float*       __restrict__ aggr,
    int E)
{
    const int lane   = threadIdx.x & 63;
    const int wave   = blockIdx.x * 4 + (threadIdx.x >> 6);
    const int nwaves = gridDim.x * 4;

    float we[EDIM];
#pragma unroll
    for (int k = 0; k < EDIM; ++k) we[k] = W_edge[k * D + lane];
    const float be = b_edge[lane];

    for (int i = wave; i < E; i += nwaves) {
        const int s = src[i];
        const int d = dst[i];
        const float4* eap = (const float4*)(edge_attr + (size_t)i * EDIM);
        float acc = be;
#pragma unroll
        for (int c = 0; c < 4; ++c) {
            const float4 ea = eap[c];
            acc = fmaf(ea.x, we[4 * c + 0], acc);
            acc = fmaf(ea.y, we[4 * c + 1], acc);
            acc = fmaf(ea.z, we[4 * c + 2], acc);
            acc = fmaf(ea.w, we[4 * c + 3], acc);
        }
        float m = fmaxf(x[(size_t)s * D + lane] + acc, 0.0f);
        atomicAdd(&aggr[(size_t)d * D + lane], m);
    }
}

__global__ __launch_bounds__(256) void add_x_kernel(
    const float* __restrict__ x, float* __restrict__ h, size_t n)
{
    size_t i = (size_t)blockIdx.x * blockDim.x + threadIdx.x;
    size_t stride = (size_t)gridDim.x * blockDim.x;
    for (; i < n; i += stride) h[i] += x[i];
}

// ---------------------------------------------------------------------------
// d_ws layout: rec[E] int2 | coarse[kc*BCAP] ll | xh[N*D] half | meta[N] int2
//              | gcursor[256*16] int
// total = 12.8 + 14.45 + 12.8 + 0.8 + 0.016 ~= 40.9 MB.
// ---------------------------------------------------------------------------
extern "C" void kernel_launch(void* const* d_in, const int* in_sizes, int n_in,
                              void* d_out, int out_size, void* d_ws, size_t ws_size,
                              hipStream_t stream)
{
    const float* x      = (const float*)d_in[0];
    const int*   eidx   = (const int*)d_in[1];
    const float* eattr  = (const float*)d_in[2];
    const float* W_edge = (const float*)d_in[3];
    const float* b_edge = (const float*)d_in[4];
    const float* W1     = (const float*)d_in[5];
    const float* b1     = (const float*)d_in[6];
    const float* W2     = (const float*)d_in[7];
    const float* b2     = (const float*)d_in[8];
    float*       out    = (float*)d_out;

    const int E = in_sizes[1] / 2;      // 1,600,000
    const int N = in_sizes[0] / D;      // 100,000

    const int* src = eidx;
    const int* dst = eidx + E;

    const int kc = (N + BRANGE - 1) >> BSHIFT;   // coarse bucket count (196)

    const size_t sz_rec    = (size_t)E * sizeof(int2);
    const size_t sz_coarse = (size_t)kc * BCAP * sizeof(long long);
    const size_t sz_xh     = (size_t)N * D * sizeof(__half);
    const size_t sz_meta   = (size_t)N * sizeof(int2);
    const size_t sz_gcur   = 256 * 16 * sizeof(int);
    const size_t need      = sz_rec + sz_coarse + sz_xh + sz_meta + sz_gcur;

    if (ws_size >= need) {
        char* p = (char*)d_ws;
        int2*      rec     = (int2*)p;                      p += sz_rec;
        long long* coarse  = (long long*)p;                 p += sz_coarse;
        __half*    xh      = (__half*)p;                    p += sz_xh;
        int2*      meta    = (int2*)p;                      p += sz_meta;
        int*       gcursor = (int*)p;

        hipMemsetAsync(gcursor, 0, sz_gcur, stream);
        convert_x_kernel<<<1024, 256, 0, stream>>>(x, xh, N * D / 4);
        const int gridA = (E + T_A - 1) / T_A;
        coarse_bin_kernel<<<gridA, 256, 0, stream>>>(dst, src, coarse, gcursor, E);
        refine_csr_kernel<<<kc, 1024, BCAP * sizeof(long long), stream>>>(
            coarse, gcursor, rec, meta, N, kc);
        gather_mlp_kernel<<<4096, 256, 0, stream>>>(x, xh, rec, meta,
                                                    eattr, W_edge, b_edge,
                                                    W1, b1, W2, b2, out, N);
    } else {
        // Fallback: atomic path (3 dispatches + memset).
        hipMemsetAsync(out, 0, (size_t)N * D * sizeof(float), stream);
        edge_atomic_kernel<<<2048, 256, 0, stream>>>(x, src, dst, eattr,
                                                     W_edge, b_edge, out, E);
        add_x_kernel<<<1024, 256, 0, stream>>>(x, out, (size_t)N * D);
        mlp_kernel<<<2048, 256, 0, stream>>>(W1, b1, W2, b2, out, N);
    }
}

// Round 8
// 400.613 us; speedup vs baseline: 1.0616x; 1.0239x over previous
//
#include <hip/hip_runtime.h>
#include <hip/hip_fp16.h>

#define D 64
#define EDIM 16
#define CAP 64      // fallback-path only

// Two-level binning parameters
#define T_A    2048   // edges per coarse-bin tile (8 per thread)
#define BSHIFT 9      // 512 nodes per coarse bucket
#define BRANGE 512
#define BCAP   9216   // coarse-bucket capacity: Poisson(8192) + 11 sigma

// ---------------------------------------------------------------------------
// Phase 0: x -> fp16 copy (sequential). Halves the random x-row footprint.
// ---------------------------------------------------------------------------
__global__ __launch_bounds__(256) void convert_x_kernel(
    const float* __restrict__ x, __half* __restrict__ xh, int n4)
{
    int i = blockIdx.x * blockDim.x + threadIdx.x;
    const int stride = gridDim.x * blockDim.x;
    for (; i < n4; i += stride) {
        const float4 v = ((const float4*)x)[i];
        __half2 a = __float22half2_rn(make_float2(v.x, v.y));
        __half2 b = __float22half2_rn(make_float2(v.z, v.w));
        uint2 u;
        u.x = *(unsigned*)&a;
        u.y = *(unsigned*)&b;
        ((uint2*)xh)[i] = u;
    }
}

// ---------------------------------------------------------------------------
// Phase 1a: coarse bin. LDS-staged counting sort into ~196 coarse buckets.
// Record pack: src[0:17) | eid[17:38) | dst_lo[38:47)
// ---------------------------------------------------------------------------
__global__ __launch_bounds__(256) void coarse_bin_kernel(
    const int* __restrict__ dst, const int* __restrict__ src,
    long long* __restrict__ coarse, int* __restrict__ gcursor, int E)
{
    __shared__ long long      stage[T_A];
    __shared__ unsigned short stage_b[T_A];
    __shared__ int lcnt[256];
    __shared__ int loff[256];
    __shared__ int lbase[256];
    __shared__ int s_valid;

    const int t    = threadIdx.x;
    const int base = blockIdx.x * T_A;

    lcnt[t] = 0;
    __syncthreads();

    int       myb[8];
    int       myslot[8];
    long long myrec[8];
#pragma unroll
    for (int j = 0; j < 8; ++j) {
        const int i = base + t + j * 256;
        if (i < E) {
            const int d = dst[i];
            const int s = src[i];
            const int b = d >> BSHIFT;
            myb[j]   = b;
            myrec[j] = (long long)(unsigned)s
                     | ((long long)i << 17)
                     | ((long long)(d & (BRANGE - 1)) << 38);
            myslot[j] = atomicAdd(&lcnt[b], 1);
        } else {
            myb[j] = -1;
        }
    }
    __syncthreads();

    // exclusive scan of lcnt over 256 entries
    const int v = lcnt[t];
    loff[t] = v;
    __syncthreads();
    for (int off = 1; off < 256; off <<= 1) {
        const int add = (t >= off) ? loff[t - off] : 0;
        __syncthreads();
        loff[t] += add;
        __syncthreads();
    }
    if (t == 255) s_valid = loff[255];
    const int excl = loff[t] - v;
    loff[t] = excl;
    if (v > 0) lbase[t] = atomicAdd(&gcursor[t * 16], v);
    else       lbase[t] = 0;
    __syncthreads();

#pragma unroll
    for (int j = 0; j < 8; ++j) {
        if (myb[j] >= 0) {
            const int p = loff[myb[j]] + myslot[j];
            stage[p]   = myrec[j];
            stage_b[p] = (unsigned short)myb[j];
        }
    }
    __syncthreads();

    const int nv = s_valid;
    for (int p = t; p < nv; p += 256) {
        const int b   = stage_b[p];
        const int rel = lbase[b] + (p - loff[b]);
        if (rel < BCAP)
            coarse[(size_t)b * BCAP + rel] = stage[p];
    }
}

// ---------------------------------------------------------------------------
// Phase 1b: refine -> dense CSR + EDGE-ATTR PRE-GATHER (R7 lesson: gather is
// bound by its chained random loads, not traffic; refine's random ea reads
// are INDEPENDENT and latency-hidable). For each CSR slot: srcs[i] = src,
// ea16[i] = fp16(edge_attr[eid]) (32 B, coalesced seq write). gather then
// streams srcs+ea16 sequentially; only xh remains random.
// ---------------------------------------------------------------------------
__global__ __launch_bounds__(1024) void refine_csr_kernel(
    const long long* __restrict__ coarse, const int* __restrict__ gcursor,
    const float* __restrict__ edge_attr,
    int* __restrict__ srcs, __half* __restrict__ ea16,
    int2* __restrict__ meta, int N, int kc)
{
    extern __shared__ long long dense[];          // BCAP records (73.7 KB)
    __shared__ int lc[BRANGE];
    __shared__ int bs[BRANGE];
    __shared__ int gb[256];

    const int t = threadIdx.x;
    const int b = blockIdx.x;

    if (t < BRANGE) lc[t] = 0;
    if (t < 256) gb[t] = (t < kc) ? min(gcursor[t * 16], BCAP) : 0;
    __syncthreads();

    // inclusive scan of gb[256]
    for (int off = 1; off < 256; off <<= 1) {
        int add = 0;
        if (t < 256 && t >= off) add = gb[t - off];
        __syncthreads();
        if (t < 256) gb[t] += add;
        __syncthreads();
    }
    const int bstart = (b == 0) ? 0 : gb[b - 1];
    const int m      = min(gcursor[b * 16], BCAP);
    const long long* crs = coarse + (size_t)b * BCAP;

    long long rp[9];
    int       rslot[9];
    int       rdlo[9];
    int       nmine = 0;
#pragma unroll
    for (int j = 0; j < 9; ++j) {               // 9*1024 >= BCAP
        const int i = t + j * 1024;
        if (i < m) {
            const long long p = crs[i];
            const int dlo = (int)((p >> 38) & (BRANGE - 1));
            rp[j]    = p;
            rdlo[j]  = dlo;
            rslot[j] = atomicAdd(&lc[dlo], 1);
            nmine    = j + 1;
        }
    }
    __syncthreads();

    // exclusive scan of lc[512] -> bs[512]
    if (t < BRANGE) bs[t] = lc[t];
    __syncthreads();
    for (int off = 1; off < BRANGE; off <<= 1) {
        int add = 0;
        if (t < BRANGE && t >= off) add = bs[t - off];
        __syncthreads();
        if (t < BRANGE) bs[t] += add;
        __syncthreads();
    }
    if (t < BRANGE) bs[t] -= lc[t];
    __syncthreads();

    // place records dense-sorted (node-major) in LDS
#pragma unroll
    for (int j = 0; j < 9; ++j) {
        if (j < nmine)
            dense[bs[rdlo[j]] + rslot[j]] = rp[j];
    }
    __syncthreads();

    // copy-out in CSR order: srcs (coalesced 4B) + pre-gathered fp16 ea rows
    // (random 64B read of edge_attr, independent across threads; coalesced
    //  32B write).
    for (int i = t; i < m; i += 1024) {
        const long long p = dense[i];
        const int s   = (int)(p & 0x1FFFF);
        const int eid = (int)((p >> 17) & 0x1FFFFF);
        srcs[bstart + i] = s;

        const float4* ap = (const float4*)(edge_attr + (size_t)eid * EDIM);
        const float4 a0 = ap[0], a1 = ap[1], a2 = ap[2], a3 = ap[3];
        __half2 h0 = __float22half2_rn(make_float2(a0.x, a0.y));
        __half2 h1 = __float22half2_rn(make_float2(a0.z, a0.w));
        __half2 h2 = __float22half2_rn(make_float2(a1.x, a1.y));
        __half2 h3 = __float22half2_rn(make_float2(a1.z, a1.w));
        __half2 h4 = __float22half2_rn(make_float2(a2.x, a2.y));
        __half2 h5 = __float22half2_rn(make_float2(a2.z, a2.w));
        __half2 h6 = __float22half2_rn(make_float2(a3.x, a3.y));
        __half2 h7 = __float22half2_rn(make_float2(a3.z, a3.w));
        uint4 q0, q1;
        q0.x = *(unsigned*)&h0; q0.y = *(unsigned*)&h1;
        q0.z = *(unsigned*)&h2; q0.w = *(unsigned*)&h3;
        q1.x = *(unsigned*)&h4; q1.y = *(unsigned*)&h5;
        q1.z = *(unsigned*)&h6; q1.w = *(unsigned*)&h7;
        uint4* dst16 = (uint4*)(ea16 + (size_t)(bstart + i) * EDIM);
        dst16[0] = q0;
        dst16[1] = q1;
    }
    if (t < BRANGE) {
        const int node = (b << BSHIFT) + t;
        if (node < N) meta[node] = make_int2(bstart + bs[t], lc[t]);
    }
}

// ---------------------------------------------------------------------------
// Phase 2 (FUSED): gather-aggregate + 2-layer node MLP.
// Loads per 4-edge group: srcs (seq, 16 B), ea16 (seq, 128 B contiguous),
// xh (random, the only scatter left). Residual x stays fp32.
// ---------------------------------------------------------------------------
__global__ __launch_bounds__(256, 4) void gather_mlp_kernel(
    const float*  __restrict__ x,
    const __half* __restrict__ xh,
    const int*    __restrict__ srcs,
    const __half* __restrict__ ea16,
    const int2*   __restrict__ meta,
    const float*  __restrict__ W_edge,
    const float*  __restrict__ b_edge,
    const float* __restrict__ W1, const float* __restrict__ b1,
    const float* __restrict__ W2, const float* __restrict__ b2,
    float*       __restrict__ out,
    int N)
{
    __shared__ float W1s[D * D];
    __shared__ float W2s[D * D];
    __shared__ float hstage[4][D];
    __shared__ float tstage[4][D];

    const int t = threadIdx.x;
    {
        const float4* w1v = (const float4*)W1;
        const float4* w2v = (const float4*)W2;
        float4* w1s = (float4*)W1s;
        float4* w2s = (float4*)W2s;
#pragma unroll
        for (int i = 0; i < 4; ++i) {
            w1s[t + i * 256] = w1v[t + i * 256];
            w2s[t + i * 256] = w2v[t + i * 256];
        }
    }
    __syncthreads();   // uniform, before the divergent node loop

    const int lane = t & 63;
    const int u    = lane >> 4;      // edge slot in group-of-4
    const int c    = lane & 15;      // column quad
    const int wv   = t >> 6;
    const int wave   = blockIdx.x * 4 + wv;
    const int nwaves = gridDim.x * 4;

    float4 we[EDIM];
#pragma unroll
    for (int k = 0; k < EDIM; ++k)
        we[k] = *(const float4*)(W_edge + k * D + 4 * c);
    const float4 be  = *(const float4*)(b_edge + 4 * c);
    const float  b1v = b1[lane];
    const float  b2v = b2[lane];

    for (int n = wave; n < N; n += nwaves) {
        const int2 md  = meta[n];
        const int  deg = md.y;
        float4 acc = make_float4(0.0f, 0.0f, 0.0f, 0.0f);

        for (int e = 0; e < deg; e += 4) {
            const int   ee  = e + u;
            const bool  ok  = ee < deg;
            const int   ec  = ok ? ee : (deg - 1);   // deg >= 1 inside loop
            const float msk = ok ? 1.0f : 0.0f;
            const int   pos = md.x + ec;

            const int s = srcs[pos];

            // fp16 x row: 8 B per lane (2 lines per row, random)
            const uint2 xu = *(const uint2*)(xh + (size_t)s * D + 4 * c);
            const float2 f01 = __half22float2(*(const __half2*)&xu.x);
            const float2 f23 = __half22float2(*(const __half2*)&xu.y);

            // fp16 ea row: 32 B, sequential in CSR order (4 edges = 128 B)
            const uint4* eap = (const uint4*)(ea16 + (size_t)pos * EDIM);
            const uint4 q0 = eap[0], q1 = eap[1];
            const float2 e0 = __half22float2(*(const __half2*)&q0.x);
            const float2 e1 = __half22float2(*(const __half2*)&q0.y);
            const float2 e2 = __half22float2(*(const __half2*)&q0.z);
            const float2 e3 = __half22float2(*(const __half2*)&q0.w);
            const float2 e4 = __half22float2(*(const __half2*)&q1.x);
            const float2 e5 = __half22float2(*(const __half2*)&q1.y);
            const float2 e6 = __half22float2(*(const __half2*)&q1.z);
            const float2 e7 = __half22float2(*(const __half2*)&q1.w);
            const float av[EDIM] = {e0.x, e0.y, e1.x, e1.y,
                                    e2.x, e2.y, e3.x, e3.y,
                                    e4.x, e4.y, e5.x, e5.y,
                                    e6.x, e6.y, e7.x, e7.y};
            float4 v = be;
#pragma unroll
            for (int k = 0; k < EDIM; ++k) {
                v.x = fmaf(av[k], we[k].x, v.x);
                v.y = fmaf(av[k], we[k].y, v.y);
                v.z = fmaf(av[k], we[k].z, v.z);
                v.w = fmaf(av[k], we[k].w, v.w);
            }
            acc.x = fmaf(fmaxf(f01.x + v.x, 0.0f), msk, acc.x);
            acc.y = fmaf(fmaxf(f01.y + v.y, 0.0f), msk, acc.y);
            acc.z = fmaf(fmaxf(f23.x + v.z, 0.0f), msk, acc.z);
            acc.w = fmaf(fmaxf(f23.y + v.w, 0.0f), msk, acc.w);
        }

        // reduce across the 4 edge slots (lane bits 4 and 5)
#pragma unroll
        for (int off = 16; off < 64; off <<= 1) {
            acc.x += __shfl_xor(acc.x, off, 64);
            acc.y += __shfl_xor(acc.y, off, 64);
            acc.z += __shfl_xor(acc.z, off, 64);
            acc.w += __shfl_xor(acc.w, off, 64);
        }

        // h = x[n] + aggr (residual in exact fp32), staged into per-wave LDS
        if (u == 0) {
            const float4 xn = *(const float4*)(x + (size_t)n * D + 4 * c);
            float4 o;
            o.x = xn.x + acc.x;
            o.y = xn.y + acc.y;
            o.z = xn.z + acc.z;
            o.w = xn.w + acc.w;
            *(float4*)(&hstage[wv][4 * c]) = o;
        }
        asm volatile("s_waitcnt lgkmcnt(0)" ::: "memory");

        // MLP layer 1: a1 = relu(h . W1[:,lane] + b1[lane])
        float acc1 = b1v;
#pragma unroll
        for (int k = 0; k < D; k += 4) {
            const float4 hv = *(const float4*)(&hstage[wv][k]);
            acc1 = fmaf(hv.x, W1s[(k + 0) * D + lane], acc1);
            acc1 = fmaf(hv.y, W1s[(k + 1) * D + lane], acc1);
            acc1 = fmaf(hv.z, W1s[(k + 2) * D + lane], acc1);
            acc1 = fmaf(hv.w, W1s[(k + 3) * D + lane], acc1);
        }
        tstage[wv][lane] = fmaxf(acc1, 0.0f);
        asm volatile("s_waitcnt lgkmcnt(0)" ::: "memory");

        // MLP layer 2: out = t . W2[:,lane] + b2[lane]
        float acc2 = b2v;
#pragma unroll
        for (int k = 0; k < D; k += 4) {
            const float4 tv = *(const float4*)(&tstage[wv][k]);
            acc2 = fmaf(tv.x, W2s[(k + 0) * D + lane], acc2);
            acc2 = fmaf(tv.y, W2s[(k + 1) * D + lane], acc2);
            acc2 = fmaf(tv.z, W2s[(k + 2) * D + lane], acc2);
            acc2 = fmaf(tv.w, W2s[(k + 3) * D + lane], acc2);
        }
        out[(size_t)n * D + lane] = acc2;
        asm volatile("s_waitcnt lgkmcnt(0)" ::: "memory");  // guard hstage reuse
    }
}

// ---------------------------------------------------------------------------
// Standalone MLP (fallback path only).
// ---------------------------------------------------------------------------
__global__ __launch_bounds__(256) void mlp_kernel(
    const float* __restrict__ W1, const float* __restrict__ b1,
    const float* __restrict__ W2, const float* __restrict__ b2,
    float* inout, int N)
{
    __shared__ float W1s[D * D];
    __shared__ float W2s[D * D];
    __shared__ float hbuf[4][D];
    __shared__ float tbuf[4][D];

    const int t = threadIdx.x;
    const float4* w1v = (const float4*)W1;
    const float4* w2v = (const float4*)W2;
    float4* w1s = (float4*)W1s;
    float4* w2s = (float4*)W2s;
#pragma unroll
    for (int i = 0; i < 4; ++i) {
        w1s[t + i * 256] = w1v[t + i * 256];
        w2s[t + i * 256] = w2v[t + i * 256];
    }
    __syncthreads();

    const int lane = t & 63;
    const int wv   = t >> 6;
    const float b1v = b1[lane];
    const float b2v = b2[lane];

    for (int base = blockIdx.x * 4; base < N; base += gridDim.x * 4) {
        const int    node = base + wv;
        const size_t off  = (size_t)node * D + lane;

        hbuf[wv][lane] = inout[off];
        __syncthreads();

        float acc = b1v;
#pragma unroll
        for (int k = 0; k < D; k += 4) {
            const float4 hv = *(const float4*)(&hbuf[wv][k]);
            acc = fmaf(hv.x, W1s[(k + 0) * D + lane], acc);
            acc = fmaf(hv.y, W1s[(k + 1) * D + lane], acc);
            acc = fmaf(hv.z, W1s[(k + 2) * D + lane], acc);
            acc = fmaf(hv.w, W1s[(k + 3) * D + lane], acc);
        }
        tbuf[wv][lane] = fmaxf(acc, 0.0f);
        __syncthreads();

        float acc2 = b2v;
#pragma unroll
        for (int k = 0; k < D; k += 4) {
            const float4 tv = *(const float4*)(&tbuf[wv][k]);
            acc2 = fmaf(tv.x, W2s[(k + 0) * D + lane], acc2);
            acc2 = fmaf(tv.y, W2s[(k + 1) * D + lane], acc2);
            acc2 = fmaf(tv.z, W2s[(k + 2) * D + lane], acc2);
            acc2 = fmaf(tv.w, W2s[(k + 3) * D + lane], acc2);
        }
        inout[off] = acc2;
        __syncthreads();
    }
}

// ---------------------------------------------------------------------------
// Fallback path kernels (only if ws_size too small — not expected).
// ---------------------------------------------------------------------------
__global__ __launch_bounds__(256) void edge_atomic_kernel(
    const float* __restrict__ x,
    const int*   __restrict__ src,
    const int*   __restrict__ dst,
    const float* __restrict__ edge_attr,
    const float* __restrict__ W_edge,
    const float* __restrict__ b_edge,
    float*       __restrict__ aggr,
    int E)
{
    const int lane   = threadIdx.x & 63;
    const int wave   = blockIdx.x * 4 + (threadIdx.x >> 6);
    const int nwaves = gridDim.x * 4;

    float we[EDIM];
#pragma unroll
    for (int k = 0; k < EDIM; ++k) we[k] = W_edge[k * D + lane];
    const float be = b_edge[lane];

    for (int i = wave; i < E; i += nwaves) {
        const int s = src[i];
        const int d = dst[i];
        const float4* eap = (const float4*)(edge_attr + (size_t)i * EDIM);
        float acc = be;
#pragma unroll
        for (int c = 0; c < 4; ++c) {
            const float4 ea = eap[c];
            acc = fmaf(ea.x, we[4 * c + 0], acc);
            acc = fmaf(ea.y, we[4 * c + 1], acc);
            acc = fmaf(ea.z, we[4 * c + 2], acc);
            acc = fmaf(ea.w, we[4 * c + 3], acc);
        }
        float m = fmaxf(x[(size_t)s * D + lane] + acc, 0.0f);
        atomicAdd(&aggr[(size_t)d * D + lane], m);
    }
}

__global__ __launch_bounds__(256) void add_x_kernel(
    const float* __restrict__ x, float* __restrict__ h, size_t n)
{
    size_t i = (size_t)blockIdx.x * blockDim.x + threadIdx.x;
    size_t stride = (size_t)gridDim.x * blockDim.x;
    for (; i < n; i += stride) h[i] += x[i];
}

// ---------------------------------------------------------------------------
// d_ws layout: ea16[E*16] half | coarse[kc*BCAP] ll | xh[N*D] half |
//              srcs[E] int | meta[N] int2 | gcursor[256*16] int
// total = 51.2 + 14.45 + 12.8 + 6.4 + 0.8 + 0.016 ~= 85.7 MB.
// ---------------------------------------------------------------------------
extern "C" void kernel_launch(void* const* d_in, const int* in_sizes, int n_in,
                              void* d_out, int out_size, void* d_ws, size_t ws_size,
                              hipStream_t stream)
{
    const float* x      = (const float*)d_in[0];
    const int*   eidx   = (const int*)d_in[1];
    const float* eattr  = (const float*)d_in[2];
    const float* W_edge = (const float*)d_in[3];
    const float* b_edge = (const float*)d_in[4];
    const float* W1     = (const float*)d_in[5];
    const float* b1     = (const float*)d_in[6];
    const float* W2     = (const float*)d_in[7];
    const float* b2     = (const float*)d_in[8];
    float*       out    = (float*)d_out;

    const int E = in_sizes[1] / 2;      // 1,600,000
    const int N = in_sizes[0] / D;      // 100,000

    const int* src = eidx;
    const int* dst = eidx + E;

    const int kc = (N + BRANGE - 1) >> BSHIFT;   // coarse bucket count (196)

    const size_t sz_ea16   = (size_t)E * EDIM * sizeof(__half);
    const size_t sz_coarse = (size_t)kc * BCAP * sizeof(long long);
    const size_t sz_xh     = (size_t)N * D * sizeof(__half);
    const size_t sz_srcs   = (size_t)E * sizeof(int);
    const size_t sz_meta   = (size_t)N * sizeof(int2);
    const size_t sz_gcur   = 256 * 16 * sizeof(int);
    const size_t need = sz_ea16 + sz_coarse + sz_xh + sz_srcs + sz_meta + sz_gcur;

    if (ws_size >= need) {
        char* p = (char*)d_ws;
        __half*    ea16    = (__half*)p;                    p += sz_ea16;
        long long* coarse  = (long long*)p;                 p += sz_coarse;
        __half*    xh      = (__half*)p;                    p += sz_xh;
        int*       srcs    = (int*)p;                       p += sz_srcs;
        int2*      meta    = (int2*)p;                      p += sz_meta;
        int*       gcursor = (int*)p;

        hipMemsetAsync(gcursor, 0, sz_gcur, stream);
        convert_x_kernel<<<1024, 256, 0, stream>>>(x, xh, N * D / 4);
        const int gridA = (E + T_A - 1) / T_A;
        coarse_bin_kernel<<<gridA, 256, 0, stream>>>(dst, src, coarse, gcursor, E);
        refine_csr_kernel<<<kc, 1024, BCAP * sizeof(long long), stream>>>(
            coarse, gcursor, eattr, srcs, ea16, meta, N, kc);
        gather_mlp_kernel<<<4096, 256, 0, stream>>>(x, xh, srcs, ea16, meta,
                                                    W_edge, b_edge,
                                                    W1, b1, W2, b2, out, N);
    } else {
        // Fallback: atomic path (3 dispatches + memset).
        hipMemsetAsync(out, 0, (size_t)N * D * sizeof(float), stream);
        edge_atomic_kernel<<<2048, 256, 0, stream>>>(x, src, dst, eattr,
                                                     W_edge, b_edge, out, E);
        add_x_kernel<<<1024, 256, 0, stream>>>(x, out, (size_t)N * D);
        mlp_kernel<<<2048, 256, 0, stream>>>(W1, b1, W2, b2, out, N);
    }
}